// Round 6
// baseline (102.171 us; speedup 1.0000x reference)
//
#include <hip/hip_runtime.h>

#define BATCH 4
#define NPTS 4096
#define DF 64
#define ITILE 128              // 4 waves x 32 rows
#define JSPLIT 8               // jc == XCD (id%8 == blockIdx.x%8 == jc)
#define JSUB 2                 // j-chunk halves -> 2048 blocks total
#define JCH (NPTS/JSPLIT)      // 512
#define JHALF (JCH/JSUB)       // 256
#define JT 32
#define NT (JHALF/JT)          // 8
#define AUGD 96                // 80 feature (5x K16) + 16 spatial (1x K16)
#define LDSPITCH 104           // 208B row stride
#define LOG2E 1.4426950408889634f

typedef short short8 __attribute__((ext_vector_type(8)));
typedef float f32x16 __attribute__((ext_vector_type(16)));

__device__ __forceinline__ unsigned short bfb(float x){
  unsigned int u = __float_as_uint(x);
  u += 0x7FFFu + ((u>>16)&1u);          // RNE
  return (unsigned short)(u>>16);
}
__device__ __forceinline__ float bff(unsigned short h){
  return __uint_as_float(((unsigned int)h)<<16);
}
__device__ __forceinline__ float fexp2(float x){   // raw v_exp_f32 (2^x)
  float r; asm("v_exp_f32 %0, %1" : "=v"(r) : "v"(x)); return r;
}

// ---------------------------------------------------------------- prepass ---
// Scores in log2 domain; log2e folded at fp32 precision into I-side products
// and J-side norm splits (bf16 multiplier slots stay exactly -1.0).
//  accF = log2e*(2*f1.f2 - |f2|^2) ; accS = log2e*(2*xs_i.xs_j - |xs_j|^2)
__global__ void df_prep(const float* __restrict__ pts,
                        const float* __restrict__ f1,
                        const float* __restrict__ f2,
                        unsigned short* __restrict__ augI,
                        unsigned short* __restrict__ augJ,
                        float* __restrict__ nsA)
{
  int wid = (blockIdx.x<<2) + (threadIdx.x>>6);
  int lane = threadIdx.x & 63;
  if (wid >= BATCH*NPTS) return;
  float v1 = f1[(size_t)wid*DF + lane];
  float v2 = f2[(size_t)wid*DF + lane];
  float r2 = v2*v2;
  #pragma unroll
  for (int s=32;s>=1;s>>=1)
    r2 += __shfl_xor(r2, s);
  augI[(size_t)wid*AUGD + lane] = bfb(2.0f*LOG2E*v1);
  augJ[(size_t)wid*AUGD + lane] = bfb(v2);
  if (lane==0){
    float px = pts[(size_t)wid*3+0]/0.05f;
    float py = pts[(size_t)wid*3+1]/0.05f;
    float pz = pts[(size_t)wid*3+2]/0.05f;
    float nss = px*px+py*py+pz*pz;
    nsA[wid]=LOG2E*nss;
    unsigned short* tI = augI + (size_t)wid*AUGD;
    unsigned short* tJ = augJ + (size_t)wid*AUGD;
    float fn = LOG2E*r2;
    unsigned short a0 = bfb(fn); float rem = fn - bff(a0);
    unsigned short a1 = bfb(rem); rem -= bff(a1);
    unsigned short a2 = bfb(rem);
    tJ[64]=a0; tJ[65]=a1; tJ[66]=a2;
    #pragma unroll
    for (int k=67;k<80;k++) tJ[k]=0;
    unsigned short hx=bfb(px), hy=bfb(py), hz=bfb(pz);
    float lx = px-bff(hx), ly = py-bff(hy), lz = pz-bff(hz);
    unsigned short lxb=bfb(lx), lyb=bfb(ly), lzb=bfb(lz);
    tJ[80]=hx; tJ[81]=hy; tJ[82]=hz;
    tJ[83]=lxb;tJ[84]=lyb;tJ[85]=lzb;
    tJ[86]=hx; tJ[87]=hy; tJ[88]=hz;
    tJ[89]=lxb;tJ[90]=lyb;tJ[91]=lzb;
    float sn = LOG2E*nss;
    a0 = bfb(sn); rem = sn - bff(a0);
    a1 = bfb(rem); rem -= bff(a1);
    a2 = bfb(rem);
    tJ[92]=a0; tJ[93]=a1; tJ[94]=a2; tJ[95]=0;
    unsigned short mone = bfb(-1.0f);
    tI[64]=mone; tI[65]=mone; tI[66]=mone;
    #pragma unroll
    for (int k=67;k<80;k++) tI[k]=0;
    float sx = 2.f*LOG2E*px, sy = 2.f*LOG2E*py, sz = 2.f*LOG2E*pz;
    unsigned short h2x=bfb(sx), h2y=bfb(sy), h2z=bfb(sz);
    float l2xf = sx-bff(h2x), l2yf = sy-bff(h2y), l2zf = sz-bff(h2z);
    unsigned short l2x=bfb(l2xf), l2y=bfb(l2yf), l2z=bfb(l2zf);
    tI[80]=h2x; tI[81]=h2y; tI[82]=h2z;
    tI[83]=h2x; tI[84]=h2y; tI[85]=h2z;
    tI[86]=l2x; tI[87]=l2y; tI[88]=l2z;
    tI[89]=l2x; tI[90]=l2y; tI[91]=l2z;
    tI[92]=mone; tI[93]=mone; tI[94]=mone; tI[95]=0;
  }
}

// ------------------------------------------------------------------- main ---
// 256 threads (4 waves), each wave owns 32 i-rows; block stages 32-j tiles in
// double-buffered LDS. blockIdx.x = jc + 8*jsub (extent 16) so id%8 == jc:
// every block resident on XCD k reads ONLY augJ chunk k (L2-pinned).
__global__ __launch_bounds__(256, 8)
void df_main(const unsigned short* __restrict__ augI,
             const unsigned short* __restrict__ augJ,
             const float* __restrict__ nsA,
             float* __restrict__ part)
{
  __shared__ unsigned short lds[2][JT][LDSPITCH];
  const int tid = threadIdx.x;
  const int wave = tid>>6, lane = tid&63;
  const int il = lane&31, hk = lane>>5;
  const int x = blockIdx.x, it = blockIdx.y, b = blockIdx.z;
  const int jc = x & 7, jsub = x >> 3;

  const int irow = it*ITILE + wave*32 + il;
  const size_t ibase = ((size_t)(b*NPTS + irow))*AUGD;
  short8 bfr[6];
  #pragma unroll
  for (int s=0;s<6;s++)
    bfr[s] = *(const short8*)(augI + ibase + s*16 + hk*8);
  const float ns_i = nsA[b*NPTS + irow];

  const size_t jbase = ((size_t)(b*NPTS + jc*JCH + jsub*JHALF))*AUGD;

  // staging: 384 16B-chunks per 32x192B tile; thread t -> chunk t (+t+256)
  const int row1 = tid/12, c1 = tid - row1*12;
  const int g2 = tid + 256;
  const int row2 = g2/12, c2 = g2 - row2*12;

  int4 pf0, pf1;
  pf0 = *(const int4*)(augJ + jbase + row1*AUGD + c1*8);
  if (tid < 128) pf1 = *(const int4*)(augJ + jbase + row2*AUGD + c2*8);
  *(int4*)(&lds[0][row1][c1*8]) = pf0;
  if (tid < 128) *(int4*)(&lds[0][row2][c2*8]) = pf1;
  __syncthreads();

  float lP=0.f, sA=0.f, m=-1e30f, lQ=0.f, sB=0.f, sC=0.f;

  for (int t=0;t<NT;t++){
    if (t+1 < NT){                       // T14: issue next-tile loads early
      size_t tb = jbase + (size_t)(t+1)*JT*AUGD;
      pf0 = *(const int4*)(augJ + tb + row1*AUGD + c1*8);
      if (tid < 128) pf1 = *(const int4*)(augJ + tb + row2*AUGD + c2*8);
    }
    const unsigned short (*tile)[LDSPITCH] = lds[t&1];
    short8 a[6];
    #pragma unroll
    for (int s=0;s<6;s++)
      a[s] = *(const short8*)(&tile[il][s*16 + hk*8]);
    f32x16 z = {};
    f32x16 accF = __builtin_amdgcn_mfma_f32_32x32x16_bf16(a[0], bfr[0], z, 0,0,0);
    accF = __builtin_amdgcn_mfma_f32_32x32x16_bf16(a[1], bfr[1], accF,0,0,0);
    accF = __builtin_amdgcn_mfma_f32_32x32x16_bf16(a[2], bfr[2], accF,0,0,0);
    accF = __builtin_amdgcn_mfma_f32_32x32x16_bf16(a[3], bfr[3], accF,0,0,0);
    accF = __builtin_amdgcn_mfma_f32_32x32x16_bf16(a[4], bfr[4], accF,0,0,0);
    f32x16 accS = __builtin_amdgcn_mfma_f32_32x32x16_bf16(a[5], bfr[5], z,0,0,0);

    float p[16];
    float tmax = -1e30f;
    #pragma unroll
    for (int r=0;r<16;r++){
      float pv = fexp2(accS[r]-ns_i);           // spatial: max known = 0 (+eps)
      p[r]=pv;
      lP += pv;
      sA = fmaf(pv, pv, sA);
      tmax = fmaxf(tmax, accF[r]);
    }
    float mnew = fmaxf(m, tmax);
    float sg = fexp2(m - mnew);
    float sg2 = sg*sg;
    lQ *= sg; sB *= sg2; sC *= sg; m = mnew;
    #pragma unroll
    for (int r=0;r<16;r++){
      float q = fexp2(accF[r]-m);
      lQ += q;
      sB = fmaf(q,q,sB);
      sC = fmaf(p[r], q, sC);
    }
    if (t+1 < NT){
      int nb = (t+1)&1;
      *(int4*)(&lds[nb][row1][c1*8]) = pf0;
      if (tid<128) *(int4*)(&lds[nb][row2][c2*8]) = pf1;
    }
    __syncthreads();
  }

  // merge the two hk-halves (disjoint j-subsets of same i-row) in-register
  float mo  = __shfl_xor(m, 32);
  float lPo = __shfl_xor(lP,32);
  float sAo = __shfl_xor(sA,32);
  float lQo = __shfl_xor(lQ,32);
  float sBo = __shfl_xor(sB,32);
  float sCo = __shfl_xor(sC,32);
  float mm = fmaxf(m, mo);
  float s0 = fexp2(m-mm), s1 = fexp2(mo-mm);
  lP += lPo; sA += sAo;
  lQ = lQ*s0 + lQo*s1;
  sB = sB*s0*s0 + sBo*s1*s1;
  sC = sC*s0 + sCo*s1;

  if (hk==0){
    const size_t pidx = (((size_t)x)*((size_t)BATCH*NPTS)
                         + (size_t)b*NPTS + irow)*8;
    float4 v0 = {lP, sA, mm, lQ};
    float4 v1 = {sB, sC, 0.f, 0.f};
    *(float4*)(part + pidx)     = v0;    // full 32B/row -> no partial lines
    *(float4*)(part + pidx + 4) = v1;
  }
}

// ----------------------------------------------------------------- reduce ---
template<int SETS>
__global__ void df_reduce(const float* __restrict__ part,
                          const float* __restrict__ w,
                          float* __restrict__ ws2)
{
  const int jb = blockIdx.x, b = blockIdx.y;
  const int tid = threadIdx.x;
  const int i = jb*256 + tid;
  const size_t stride = (size_t)BATCH*NPTS*8;
  const size_t base = ((size_t)b*NPTS + i)*8;
  float mx = -1e30f;
  #pragma unroll
  for (int k=0;k<SETS;k++)
    mx = fmaxf(mx, part[base + (size_t)k*stride + 2]);
  float lP=0,sA=0,lQ=0,sB=0,sC=0;
  #pragma unroll
  for (int k=0;k<SETS;k++){
    const float* pp = part + base + (size_t)k*stride;
    lP += pp[0]; sA += pp[1];
    float sg = fexp2(pp[2]-mx);
    lQ += sg*pp[3]; sB += sg*sg*pp[4]; sC += sg*pp[5];
  }
  float res = sA/(lP*lP) + sB/(lQ*lQ) - 2.0f*sC/(lP*lQ);
  float acc = w[(size_t)b*NPTS + i]*res;
  __shared__ float red[256];
  red[tid]=acc; __syncthreads();
  for (int s=128;s>0;s>>=1){
    if (tid<s) red[tid]+=red[tid+s];
    __syncthreads();
  }
  if (tid==0) ws2[b*16+jb]=red[0];
}

__global__ void df_final(const float* __restrict__ ws2, float* __restrict__ out){
  int b = threadIdx.x;
  if (b < BATCH){
    float s=0.f;
    #pragma unroll
    for (int k=0;k<16;k++) s += ws2[b*16+k];
    out[b]=s;
  }
}

// ----------------------------------------------------------------- launch ---
extern "C" void kernel_launch(void* const* d_in, const int* in_sizes, int n_in,
                              void* d_out, int out_size, void* d_ws, size_t ws_size,
                              hipStream_t stream) {
  const float* pts = (const float*)d_in[0];
  const float* w   = (const float*)d_in[1];
  const float* f1  = (const float*)d_in[2];
  const float* f2  = (const float*)d_in[3];
  float* out = (float*)d_out;

  unsigned char* ws = (unsigned char*)d_ws;
  const size_t AUG_BYTES  = (size_t)BATCH*NPTS*AUGD*2;       // 3,145,728
  const size_t NORM_BYTES = (size_t)BATCH*NPTS*4;            // 65,536
  unsigned short* augI = (unsigned short*)(ws);
  unsigned short* augJ = (unsigned short*)(ws + AUG_BYTES);
  float* nsA  = (float*)(ws + 2*AUG_BYTES);
  float* part = (float*)(ws + 2*AUG_BYTES + NORM_BYTES);

  const size_t PART16 = (size_t)16*BATCH*NPTS*8*4;           // 8,388,608
  const size_t HEAD   = 2*AUG_BYTES + NORM_BYTES;
  float* ws2 = (float*)(ws + HEAD + PART16);

  df_prep<<<(BATCH*NPTS)/4, 256, 0, stream>>>(pts, f1, f2, augI, augJ, nsA);
  df_main<<<dim3(JSPLIT*JSUB, NPTS/ITILE, BATCH), 256, 0, stream>>>(augI, augJ, nsA, part);
  df_reduce<16><<<dim3(16, BATCH), 256, 0, stream>>>(part, w, ws2);
  df_final<<<1, 64, 0, stream>>>(ws2, out);
}

// Round 7
// 98.364 us; speedup vs baseline: 1.0387x; 1.0387x over previous
//
#include <hip/hip_runtime.h>

#define BATCH 4
#define NPTS 4096
#define DF 64
#define ITILE 128              // 4 waves x 32 rows
#define NIT 16                 // i-tiles per half (16*128 = 2048)
#define NJC 16                 // j-chunks (16*256 = 4096)
#define JCH (NPTS/NJC)         // 256
#define JT 32
#define NT (JCH/JT)            // 8
#define AUGD 96                // 80 feature (5x K16) + 16 spatial (1x K16)
#define LDSPITCH 104           // 208B row stride
#define LOG2E 1.4426950408889634f

typedef short short8 __attribute__((ext_vector_type(8)));
typedef float f32x16 __attribute__((ext_vector_type(16)));

__device__ __forceinline__ unsigned short bfb(float x){
  unsigned int u = __float_as_uint(x);
  u += 0x7FFFu + ((u>>16)&1u);          // RNE
  return (unsigned short)(u>>16);
}
__device__ __forceinline__ float bff(unsigned short h){
  return __uint_as_float(((unsigned int)h)<<16);
}
__device__ __forceinline__ float fexp2(float x){   // raw v_exp_f32 (2^x)
  float r; asm("v_exp_f32 %0, %1" : "=v"(r) : "v"(x)); return r;
}

// ---------------------------------------------------------------- prepass ---
// Scores in log2 domain; log2e folded at fp32 precision into I-side products
// and J-side norm splits (bf16 multiplier slots stay exactly -1.0).
//  accF = log2e*(2*f1.f2 - |f2|^2) ; accS = log2e*(2*xs_i.xs_j - |xs_j|^2)
__global__ void df_prep(const float* __restrict__ pts,
                        const float* __restrict__ f1,
                        const float* __restrict__ f2,
                        unsigned short* __restrict__ augI,
                        unsigned short* __restrict__ augJ,
                        float* __restrict__ nsA)
{
  int wid = (blockIdx.x<<2) + (threadIdx.x>>6);
  int lane = threadIdx.x & 63;
  if (wid >= BATCH*NPTS) return;
  float v1 = f1[(size_t)wid*DF + lane];
  float v2 = f2[(size_t)wid*DF + lane];
  float r2 = v2*v2;
  #pragma unroll
  for (int s=32;s>=1;s>>=1)
    r2 += __shfl_xor(r2, s);
  augI[(size_t)wid*AUGD + lane] = bfb(2.0f*LOG2E*v1);
  augJ[(size_t)wid*AUGD + lane] = bfb(v2);
  if (lane==0){
    float px = pts[(size_t)wid*3+0]/0.05f;
    float py = pts[(size_t)wid*3+1]/0.05f;
    float pz = pts[(size_t)wid*3+2]/0.05f;
    float nss = px*px+py*py+pz*pz;
    nsA[wid]=LOG2E*nss;
    unsigned short* tI = augI + (size_t)wid*AUGD;
    unsigned short* tJ = augJ + (size_t)wid*AUGD;
    float fn = LOG2E*r2;
    unsigned short a0 = bfb(fn); float rem = fn - bff(a0);
    unsigned short a1 = bfb(rem); rem -= bff(a1);
    unsigned short a2 = bfb(rem);
    tJ[64]=a0; tJ[65]=a1; tJ[66]=a2;
    #pragma unroll
    for (int k=67;k<80;k++) tJ[k]=0;
    unsigned short hx=bfb(px), hy=bfb(py), hz=bfb(pz);
    float lx = px-bff(hx), ly = py-bff(hy), lz = pz-bff(hz);
    unsigned short lxb=bfb(lx), lyb=bfb(ly), lzb=bfb(lz);
    tJ[80]=hx; tJ[81]=hy; tJ[82]=hz;
    tJ[83]=lxb;tJ[84]=lyb;tJ[85]=lzb;
    tJ[86]=hx; tJ[87]=hy; tJ[88]=hz;
    tJ[89]=lxb;tJ[90]=lyb;tJ[91]=lzb;
    float sn = LOG2E*nss;
    a0 = bfb(sn); rem = sn - bff(a0);
    a1 = bfb(rem); rem -= bff(a1);
    a2 = bfb(rem);
    tJ[92]=a0; tJ[93]=a1; tJ[94]=a2; tJ[95]=0;
    unsigned short mone = bfb(-1.0f);
    tI[64]=mone; tI[65]=mone; tI[66]=mone;
    #pragma unroll
    for (int k=67;k<80;k++) tI[k]=0;
    float sx = 2.f*LOG2E*px, sy = 2.f*LOG2E*py, sz = 2.f*LOG2E*pz;
    unsigned short h2x=bfb(sx), h2y=bfb(sy), h2z=bfb(sz);
    float l2xf = sx-bff(h2x), l2yf = sy-bff(h2y), l2zf = sz-bff(h2z);
    unsigned short l2x=bfb(l2xf), l2y=bfb(l2yf), l2z=bfb(l2zf);
    tI[80]=h2x; tI[81]=h2y; tI[82]=h2z;
    tI[83]=h2x; tI[84]=h2y; tI[85]=h2z;
    tI[86]=l2x; tI[87]=l2y; tI[88]=l2z;
    tI[89]=l2x; tI[90]=l2y; tI[91]=l2z;
    tI[92]=mone; tI[93]=mone; tI[94]=mone; tI[95]=0;
  }
}

// ------------------------------------------------------------------- main ---
// 256 threads (4 waves), each wave owns 32 i-rows. blockIdx.x (extent 8, so
// XCD = id%8 = x) selects (b, i-half): XCD k touches ONLY augI slice 393KB +
// augJ[batch] 786KB + part slice 1MB ~= 2.2MB < 4MB L2 -> no thrash, 16x
// in-L2 reuse on both operands. y = i-tile within half, z = j-chunk.
__global__ __launch_bounds__(256, 8)
void df_main(const unsigned short* __restrict__ augI,
             const unsigned short* __restrict__ augJ,
             const float* __restrict__ nsA,
             float* __restrict__ part)
{
  __shared__ unsigned short lds[2][JT][LDSPITCH];
  const int tid = threadIdx.x;
  const int wave = tid>>6, lane = tid&63;
  const int il = lane&31, hk = lane>>5;
  const int x = blockIdx.x, it = blockIdx.y, jc = blockIdx.z;
  const int b = x>>1, ih = x&1;

  const int irow = ih*(NPTS/2) + it*ITILE + wave*32 + il;
  const size_t ibase = ((size_t)(b*NPTS + irow))*AUGD;
  short8 bfr[6];
  #pragma unroll
  for (int s=0;s<6;s++)
    bfr[s] = *(const short8*)(augI + ibase + s*16 + hk*8);
  const float ns_i = nsA[b*NPTS + irow];

  const size_t jbase = ((size_t)(b*NPTS + jc*JCH))*AUGD;

  // staging: 384 16B-chunks per 32x192B tile; thread t -> chunk t (+t+256)
  const int row1 = tid/12, c1 = tid - row1*12;
  const int g2 = tid + 256;
  const int row2 = g2/12, c2 = g2 - row2*12;

  int4 pf0, pf1;
  pf0 = *(const int4*)(augJ + jbase + row1*AUGD + c1*8);
  if (tid < 128) pf1 = *(const int4*)(augJ + jbase + row2*AUGD + c2*8);
  *(int4*)(&lds[0][row1][c1*8]) = pf0;
  if (tid < 128) *(int4*)(&lds[0][row2][c2*8]) = pf1;
  __syncthreads();

  float lP=0.f, sA=0.f, m=-1e30f, lQ=0.f, sB=0.f, sC=0.f;

  for (int t=0;t<NT;t++){
    if (t+1 < NT){                       // T14: issue next-tile loads early
      size_t tb = jbase + (size_t)(t+1)*JT*AUGD;
      pf0 = *(const int4*)(augJ + tb + row1*AUGD + c1*8);
      if (tid < 128) pf1 = *(const int4*)(augJ + tb + row2*AUGD + c2*8);
    }
    const unsigned short (*tile)[LDSPITCH] = lds[t&1];
    short8 a[6];
    #pragma unroll
    for (int s=0;s<6;s++)
      a[s] = *(const short8*)(&tile[il][s*16 + hk*8]);
    f32x16 z = {};
    f32x16 accF = __builtin_amdgcn_mfma_f32_32x32x16_bf16(a[0], bfr[0], z, 0,0,0);
    accF = __builtin_amdgcn_mfma_f32_32x32x16_bf16(a[1], bfr[1], accF,0,0,0);
    accF = __builtin_amdgcn_mfma_f32_32x32x16_bf16(a[2], bfr[2], accF,0,0,0);
    accF = __builtin_amdgcn_mfma_f32_32x32x16_bf16(a[3], bfr[3], accF,0,0,0);
    accF = __builtin_amdgcn_mfma_f32_32x32x16_bf16(a[4], bfr[4], accF,0,0,0);
    f32x16 accS = __builtin_amdgcn_mfma_f32_32x32x16_bf16(a[5], bfr[5], z,0,0,0);

    float p[16];
    float tmax = -1e30f;
    #pragma unroll
    for (int r=0;r<16;r++){
      float pv = fexp2(accS[r]-ns_i);           // spatial: max known = 0 (+eps)
      p[r]=pv;
      lP += pv;
      sA = fmaf(pv, pv, sA);
      tmax = fmaxf(tmax, accF[r]);
    }
    float mnew = fmaxf(m, tmax);
    float sg = fexp2(m - mnew);
    float sg2 = sg*sg;
    lQ *= sg; sB *= sg2; sC *= sg; m = mnew;
    #pragma unroll
    for (int r=0;r<16;r++){
      float q = fexp2(accF[r]-m);
      lQ += q;
      sB = fmaf(q,q,sB);
      sC = fmaf(p[r], q, sC);
    }
    if (t+1 < NT){
      int nb = (t+1)&1;
      *(int4*)(&lds[nb][row1][c1*8]) = pf0;
      if (tid<128) *(int4*)(&lds[nb][row2][c2*8]) = pf1;
    }
    __syncthreads();
  }

  // merge the two hk-halves (disjoint j-subsets of same i-row) in-register
  float mo  = __shfl_xor(m, 32);
  float lPo = __shfl_xor(lP,32);
  float sAo = __shfl_xor(sA,32);
  float lQo = __shfl_xor(lQ,32);
  float sBo = __shfl_xor(sB,32);
  float sCo = __shfl_xor(sC,32);
  float mm = fmaxf(m, mo);
  float s0 = fexp2(m-mm), s1 = fexp2(mo-mm);
  lP += lPo; sA += sAo;
  lQ = lQ*s0 + lQo*s1;
  sB = sB*s0*s0 + sBo*s1*s1;
  sC = sC*s0 + sCo*s1;

  if (hk==0){
    const size_t pidx = (((size_t)jc)*((size_t)BATCH*NPTS)
                         + (size_t)b*NPTS + irow)*8;
    float4 v0 = {lP, sA, mm, lQ};
    float4 v1 = {sB, sC, 0.f, 0.f};
    *(float4*)(part + pidx)     = v0;    // full 32B/row -> no partial lines
    *(float4*)(part + pidx + 4) = v1;
  }
}

// ----------------------------------------------------------------- reduce ---
template<int SETS>
__global__ void df_reduce(const float* __restrict__ part,
                          const float* __restrict__ w,
                          float* __restrict__ ws2)
{
  const int jb = blockIdx.x, b = blockIdx.y;
  const int tid = threadIdx.x;
  const int i = jb*256 + tid;
  const size_t stride = (size_t)BATCH*NPTS*8;
  const size_t base = ((size_t)b*NPTS + i)*8;
  float mx = -1e30f;
  #pragma unroll
  for (int k=0;k<SETS;k++)
    mx = fmaxf(mx, part[base + (size_t)k*stride + 2]);
  float lP=0,sA=0,lQ=0,sB=0,sC=0;
  #pragma unroll
  for (int k=0;k<SETS;k++){
    const float* pp = part + base + (size_t)k*stride;
    lP += pp[0]; sA += pp[1];
    float sg = fexp2(pp[2]-mx);
    lQ += sg*pp[3]; sB += sg*sg*pp[4]; sC += sg*pp[5];
  }
  float res = sA/(lP*lP) + sB/(lQ*lQ) - 2.0f*sC/(lP*lQ);
  float acc = w[(size_t)b*NPTS + i]*res;
  __shared__ float red[256];
  red[tid]=acc; __syncthreads();
  for (int s=128;s>0;s>>=1){
    if (tid<s) red[tid]+=red[tid+s];
    __syncthreads();
  }
  if (tid==0) ws2[b*16+jb]=red[0];
}

__global__ void df_final(const float* __restrict__ ws2, float* __restrict__ out){
  int b = threadIdx.x;
  if (b < BATCH){
    float s=0.f;
    #pragma unroll
    for (int k=0;k<16;k++) s += ws2[b*16+k];
    out[b]=s;
  }
}

// ----------------------------------------------------------------- launch ---
extern "C" void kernel_launch(void* const* d_in, const int* in_sizes, int n_in,
                              void* d_out, int out_size, void* d_ws, size_t ws_size,
                              hipStream_t stream) {
  const float* pts = (const float*)d_in[0];
  const float* w   = (const float*)d_in[1];
  const float* f1  = (const float*)d_in[2];
  const float* f2  = (const float*)d_in[3];
  float* out = (float*)d_out;

  unsigned char* ws = (unsigned char*)d_ws;
  const size_t AUG_BYTES  = (size_t)BATCH*NPTS*AUGD*2;       // 3,145,728
  const size_t NORM_BYTES = (size_t)BATCH*NPTS*4;            // 65,536
  unsigned short* augI = (unsigned short*)(ws);
  unsigned short* augJ = (unsigned short*)(ws + AUG_BYTES);
  float* nsA  = (float*)(ws + 2*AUG_BYTES);
  float* part = (float*)(ws + 2*AUG_BYTES + NORM_BYTES);

  const size_t PART16 = (size_t)16*BATCH*NPTS*8*4;           // 8,388,608
  const size_t HEAD   = 2*AUG_BYTES + NORM_BYTES;
  float* ws2 = (float*)(ws + HEAD + PART16);

  df_prep<<<(BATCH*NPTS)/4, 256, 0, stream>>>(pts, f1, f2, augI, augJ, nsA);
  // x: (b, i-half) -> XCD; y: i-tile; z: j-chunk
  df_main<<<dim3(2*BATCH, NIT, NJC), 256, 0, stream>>>(augI, augJ, nsA, part);
  df_reduce<16><<<dim3(16, BATCH), 256, 0, stream>>>(part, w, ws2);
  df_final<<<1, 64, 0, stream>>>(ws2, out);
}

// Round 8
// 55.470 us; speedup vs baseline: 1.8419x; 1.7733x over previous
//
#include <hip/hip_runtime.h>

#define BATCH 4
#define NPTS 4096
#define DF 64
#define ITILE 256              // 8 waves x 32 rows
#define JSPLIT 8
#define JCH (NPTS/JSPLIT)      // 512
#define JT 32
#define NT (JCH/JT)            // 16
#define AUGD 96                // 80 feature (5x K16) + 16 spatial (1x K16)
#define LOG2E 1.4426950408889634f

typedef short short8 __attribute__((ext_vector_type(8)));
typedef float f32x16 __attribute__((ext_vector_type(16)));

__device__ __forceinline__ unsigned short bfb(float x){
  unsigned int u = __float_as_uint(x);
  u += 0x7FFFu + ((u>>16)&1u);          // RNE
  return (unsigned short)(u>>16);
}
__device__ __forceinline__ float bff(unsigned short h){
  return __uint_as_float(((unsigned int)h)<<16);
}
__device__ __forceinline__ float fexp2(float x){   // raw v_exp_f32 (2^x)
  float r; asm("v_exp_f32 %0, %1" : "=v"(r) : "v"(x)); return r;
}

// ---------------------------------------------------------------- prepass ---
// Scores in log2 domain; log2e folded at fp32 precision into I-side products
// and J-side norm splits (bf16 multiplier slots stay exactly -1.0).
//  accF = log2e*(2*f1.f2 - |f2|^2) ; accS = log2e*(2*xs_i.xs_j - |xs_j|^2)
__global__ void df_prep(const float* __restrict__ pts,
                        const float* __restrict__ f1,
                        const float* __restrict__ f2,
                        unsigned short* __restrict__ augI,
                        unsigned short* __restrict__ augJ,
                        float* __restrict__ nsA)
{
  int wid = (blockIdx.x<<2) + (threadIdx.x>>6);
  int lane = threadIdx.x & 63;
  if (wid >= BATCH*NPTS) return;
  float v1 = f1[(size_t)wid*DF + lane];
  float v2 = f2[(size_t)wid*DF + lane];
  float r2 = v2*v2;
  #pragma unroll
  for (int s=32;s>=1;s>>=1)
    r2 += __shfl_xor(r2, s);
  augI[(size_t)wid*AUGD + lane] = bfb(2.0f*LOG2E*v1);
  augJ[(size_t)wid*AUGD + lane] = bfb(v2);
  if (lane==0){
    float px = pts[(size_t)wid*3+0]/0.05f;
    float py = pts[(size_t)wid*3+1]/0.05f;
    float pz = pts[(size_t)wid*3+2]/0.05f;
    float nss = px*px+py*py+pz*pz;
    nsA[wid]=LOG2E*nss;
    unsigned short* tI = augI + (size_t)wid*AUGD;
    unsigned short* tJ = augJ + (size_t)wid*AUGD;
    float fn = LOG2E*r2;
    unsigned short a0 = bfb(fn); float rem = fn - bff(a0);
    unsigned short a1 = bfb(rem); rem -= bff(a1);
    unsigned short a2 = bfb(rem);
    tJ[64]=a0; tJ[65]=a1; tJ[66]=a2;
    #pragma unroll
    for (int k=67;k<80;k++) tJ[k]=0;
    unsigned short hx=bfb(px), hy=bfb(py), hz=bfb(pz);
    float lx = px-bff(hx), ly = py-bff(hy), lz = pz-bff(hz);
    unsigned short lxb=bfb(lx), lyb=bfb(ly), lzb=bfb(lz);
    tJ[80]=hx; tJ[81]=hy; tJ[82]=hz;
    tJ[83]=lxb;tJ[84]=lyb;tJ[85]=lzb;
    tJ[86]=hx; tJ[87]=hy; tJ[88]=hz;
    tJ[89]=lxb;tJ[90]=lyb;tJ[91]=lzb;
    float sn = LOG2E*nss;
    a0 = bfb(sn); rem = sn - bff(a0);
    a1 = bfb(rem); rem -= bff(a1);
    a2 = bfb(rem);
    tJ[92]=a0; tJ[93]=a1; tJ[94]=a2; tJ[95]=0;
    unsigned short mone = bfb(-1.0f);
    tI[64]=mone; tI[65]=mone; tI[66]=mone;
    #pragma unroll
    for (int k=67;k<80;k++) tI[k]=0;
    float sx = 2.f*LOG2E*px, sy = 2.f*LOG2E*py, sz = 2.f*LOG2E*pz;
    unsigned short h2x=bfb(sx), h2y=bfb(sy), h2z=bfb(sz);
    float l2xf = sx-bff(h2x), l2yf = sy-bff(h2y), l2zf = sz-bff(h2z);
    unsigned short l2x=bfb(l2xf), l2y=bfb(l2yf), l2z=bfb(l2zf);
    tI[80]=h2x; tI[81]=h2y; tI[82]=h2z;
    tI[83]=h2x; tI[84]=h2y; tI[85]=h2z;
    tI[86]=l2x; tI[87]=l2y; tI[88]=l2z;
    tI[89]=l2x; tI[90]=l2y; tI[91]=l2z;
    tI[92]=mone; tI[93]=mone; tI[94]=mone; tI[95]=0;
  }
}

// ------------------------------------------------------------------- main ---
// R5 grid (proven FETCH 14MB): 512 blocks x 512 threads, x=jc, y=it, z=b.
// NO LDS, NO BARRIERS: each wave reads its j-fragments directly from global
// (augJ chunk is L2/L1-resident; all 8 waves sweep the same tiles -> L1 hits).
// Waves fully decoupled -> VALU issue-limited instead of barrier-limited.
__global__ __launch_bounds__(512, 4)
void df_main(const unsigned short* __restrict__ augI,
             const unsigned short* __restrict__ augJ,
             const float* __restrict__ nsA,
             float* __restrict__ part)
{
  const int tid = threadIdx.x;
  const int wave = tid>>6, lane = tid&63;
  const int il = lane&31, hk = lane>>5;
  const int jc = blockIdx.x, it = blockIdx.y, b = blockIdx.z;

  const int irow = it*ITILE + wave*32 + il;
  const size_t ibase = ((size_t)(b*NPTS + irow))*AUGD;
  short8 bfr[6];
  #pragma unroll
  for (int s=0;s<6;s++)
    bfr[s] = *(const short8*)(augI + ibase + s*16 + hk*8);
  const float ns_i = nsA[b*NPTS + irow];

  // per-lane fragment base: row il of the tile, col half hk
  const unsigned short* jp = augJ + ((size_t)(b*NPTS + jc*JCH) + il)*AUGD + hk*8;

  float lP=0.f, sA=0.f, m=-1e30f, lQ=0.f, sB=0.f, sC=0.f;

  for (int t=0;t<NT;t++){
    short8 a[6];
    #pragma unroll
    for (int s=0;s<6;s++)
      a[s] = *(const short8*)(jp + s*16);   // 6x b128, imm offsets 0..160B
    jp += (size_t)JT*AUGD;

    f32x16 z = {};
    f32x16 accF = __builtin_amdgcn_mfma_f32_32x32x16_bf16(a[0], bfr[0], z, 0,0,0);
    accF = __builtin_amdgcn_mfma_f32_32x32x16_bf16(a[1], bfr[1], accF,0,0,0);
    accF = __builtin_amdgcn_mfma_f32_32x32x16_bf16(a[2], bfr[2], accF,0,0,0);
    accF = __builtin_amdgcn_mfma_f32_32x32x16_bf16(a[3], bfr[3], accF,0,0,0);
    accF = __builtin_amdgcn_mfma_f32_32x32x16_bf16(a[4], bfr[4], accF,0,0,0);
    f32x16 accS = __builtin_amdgcn_mfma_f32_32x32x16_bf16(a[5], bfr[5], z,0,0,0);

    float p[16];
    float tmax = -1e30f;
    #pragma unroll
    for (int r=0;r<16;r++){
      float pv = fexp2(accS[r]-ns_i);           // spatial: max known = 0 (+eps)
      p[r]=pv;
      lP += pv;
      sA = fmaf(pv, pv, sA);
      tmax = fmaxf(tmax, accF[r]);
    }
    float mnew = fmaxf(m, tmax);
    float sg = fexp2(m - mnew);
    float sg2 = sg*sg;
    lQ *= sg; sB *= sg2; sC *= sg; m = mnew;
    #pragma unroll
    for (int r=0;r<16;r++){
      float q = fexp2(accF[r]-m);
      lQ += q;
      sB = fmaf(q,q,sB);
      sC = fmaf(p[r], q, sC);
    }
  }

  // merge the two hk-halves (disjoint j-subsets of same i-row) in-register
  float mo  = __shfl_xor(m, 32);
  float lPo = __shfl_xor(lP,32);
  float sAo = __shfl_xor(sA,32);
  float lQo = __shfl_xor(lQ,32);
  float sBo = __shfl_xor(sB,32);
  float sCo = __shfl_xor(sC,32);
  float mm = fmaxf(m, mo);
  float s0 = fexp2(m-mm), s1 = fexp2(mo-mm);
  lP += lPo; sA += sAo;
  lQ = lQ*s0 + lQo*s1;
  sB = sB*s0*s0 + sBo*s1*s1;
  sC = sC*s0 + sCo*s1;

  if (hk==0){
    const size_t pidx = (((size_t)jc)*((size_t)BATCH*NPTS)
                         + (size_t)b*NPTS + irow)*8;
    float4 v0 = {lP, sA, mm, lQ};
    float4 v1 = {sB, sC, 0.f, 0.f};
    *(float4*)(part + pidx)     = v0;    // full 32B/row -> no partial lines
    *(float4*)(part + pidx + 4) = v1;
  }
}

// ----------------------------------------------------------------- reduce ---
template<int SETS>
__global__ void df_reduce(const float* __restrict__ part,
                          const float* __restrict__ w,
                          float* __restrict__ ws2)
{
  const int jb = blockIdx.x, b = blockIdx.y;
  const int tid = threadIdx.x;
  const int i = jb*256 + tid;
  const size_t stride = (size_t)BATCH*NPTS*8;
  const size_t base = ((size_t)b*NPTS + i)*8;
  float mx = -1e30f;
  #pragma unroll
  for (int k=0;k<SETS;k++)
    mx = fmaxf(mx, part[base + (size_t)k*stride + 2]);
  float lP=0,sA=0,lQ=0,sB=0,sC=0;
  #pragma unroll
  for (int k=0;k<SETS;k++){
    const float* pp = part + base + (size_t)k*stride;
    lP += pp[0]; sA += pp[1];
    float sg = fexp2(pp[2]-mx);
    lQ += sg*pp[3]; sB += sg*sg*pp[4]; sC += sg*pp[5];
  }
  float res = sA/(lP*lP) + sB/(lQ*lQ) - 2.0f*sC/(lP*lQ);
  float acc = w[(size_t)b*NPTS + i]*res;
  __shared__ float red[256];
  red[tid]=acc; __syncthreads();
  for (int s=128;s>0;s>>=1){
    if (tid<s) red[tid]+=red[tid+s];
    __syncthreads();
  }
  if (tid==0) ws2[b*16+jb]=red[0];
}

__global__ void df_final(const float* __restrict__ ws2, float* __restrict__ out){
  int b = threadIdx.x;
  if (b < BATCH){
    float s=0.f;
    #pragma unroll
    for (int k=0;k<16;k++) s += ws2[b*16+k];
    out[b]=s;
  }
}

// ----------------------------------------------------------------- launch ---
extern "C" void kernel_launch(void* const* d_in, const int* in_sizes, int n_in,
                              void* d_out, int out_size, void* d_ws, size_t ws_size,
                              hipStream_t stream) {
  const float* pts = (const float*)d_in[0];
  const float* w   = (const float*)d_in[1];
  const float* f1  = (const float*)d_in[2];
  const float* f2  = (const float*)d_in[3];
  float* out = (float*)d_out;

  unsigned char* ws = (unsigned char*)d_ws;
  const size_t AUG_BYTES  = (size_t)BATCH*NPTS*AUGD*2;       // 3,145,728
  const size_t NORM_BYTES = (size_t)BATCH*NPTS*4;            // 65,536
  unsigned short* augI = (unsigned short*)(ws);
  unsigned short* augJ = (unsigned short*)(ws + AUG_BYTES);
  float* nsA  = (float*)(ws + 2*AUG_BYTES);
  float* part = (float*)(ws + 2*AUG_BYTES + NORM_BYTES);

  const size_t PART8 = (size_t)JSPLIT*BATCH*NPTS*8*4;        // 4,194,304
  const size_t HEAD  = 2*AUG_BYTES + NORM_BYTES;
  float* ws2 = (float*)(ws + HEAD + PART8);

  df_prep<<<(BATCH*NPTS)/4, 256, 0, stream>>>(pts, f1, f2, augI, augJ, nsA);
  df_main<<<dim3(JSPLIT, NPTS/ITILE, BATCH), 512, 0, stream>>>(augI, augJ, nsA, part);
  df_reduce<JSPLIT><<<dim3(16, BATCH), 256, 0, stream>>>(part, w, ws2);
  df_final<<<1, 64, 0, stream>>>(ws2, out);
}